// Round 3
// baseline (2319.222 us; speedup 1.0000x reference)
//
#include <hip/hip_runtime.h>
#include <hip/hip_bf16.h>

// Problem constants
#define NB 64
#define NT 256
#define TC 16
#define NL 25
#define NWORDS 16384   // NB*NT
#define DWd 150        // word-LSTM input dim
#define WEd 100

__device__ __forceinline__ float sigf(float x){ return __fdividef(1.f, 1.f + __expf(-x)); }
__device__ __forceinline__ float tanhf_(float x){
    float ax = fabsf(x);
    float e = __expf(-2.f*ax);                 // e in (0,1], overflow-safe
    float r = (1.f - e) * __fdividef(1.f, 1.f + e);
    return copysignf(r, x);
}

// ---------------- Kernel 0: gxc[c][dir][u][q] = cb[q*25+u] + sum_k char_emb[c][k]*cWih[k][q*25+u]
__global__ void k_gxc(const float* __restrict__ char_emb,
                      const float* __restrict__ cWih_f, const float* __restrict__ cb_f,
                      const float* __restrict__ cWih_b, const float* __restrict__ cb_b,
                      float* __restrict__ gxc){
  int i = blockIdx.x*blockDim.x + threadIdx.x;
  if (i >= 128*2*25*4) return;
  int q = i & 3; int t = i >> 2; int u = t % 25; int t2 = t / 25; int d = t2 & 1; int c = t2 >> 1;
  const float* Wih = d ? cWih_b : cWih_f;
  const float* bb  = d ? cb_b  : cb_f;
  int col = q*25 + u;
  float acc = bb[col];
  #pragma unroll
  for (int k=0;k<25;k++) acc += char_emb[c*25+k]*Wih[k*100+col];
  gxc[i] = acc;
}

// ---------------- Kernel 1: char BiLSTM, lane = word. One wave per (64 words, dir).
// h/c state fully in registers; weights broadcast from 10KB LDS table; gx gathered
// as one float4 per unit from L2-resident gxc. No barriers in the time loop.
// Final h == h(len-1) via predicated update. cf layout: [word][2][28] (float4-aligned).
__global__ __launch_bounds__(64) void k_char(const int* __restrict__ char_tensor,
   const int* __restrict__ char_lengths,
   const float* __restrict__ cWhh_f, const float* __restrict__ cWhh_b,
   const float* __restrict__ gxc, float* __restrict__ cf){
  __shared__ float whq[2500];   // [k][u][gate q]
  int lane = threadIdx.x;
  int gw = blockIdx.x;          // 0..511
  int d  = gw >> 8;
  int w0 = (gw & 255) * 64;
  const float* W = d ? cWhh_b : cWhh_f;
  for (int i=lane; i<2500; i+=64){
    int q = i & 3; int u = (i>>2)%25; int k = (i>>2)/25;
    whq[i] = W[k*100 + q*25 + u];
  }
  __syncthreads();
  int w = w0 + lane;
  int len = char_lengths[w];
  const int* crow = char_tensor + w*TC;
  float h[25], c[25];
  #pragma unroll
  for (int u=0;u<25;u++){ h[u]=0.f; c[u]=0.f; }
  for (int t=0;t<TC;t++){
    bool active = (t < len);
    int ci = d ? (len-1-t) : t;
    if (ci < 0) ci = 0;
    int cidx = crow[ci];
    const float4* gx4 = (const float4*)(gxc + (size_t)(cidx*2+d)*100);
    float hn[25];
    #pragma unroll
    for (int u=0;u<25;u++){
      float4 a = gx4[u];
      #pragma unroll
      for (int k=0;k<25;k++){
        float4 wv = *(const float4*)&whq[(k*25+u)*4];
        a.x += h[k]*wv.x; a.y += h[k]*wv.y;
        a.z += h[k]*wv.z; a.w += h[k]*wv.w;
      }
      float cn = sigf(a.y)*c[u] + sigf(a.x)*tanhf_(a.z);
      float hv = sigf(a.w)*tanhf_(cn);
      if (active){ c[u] = cn; hn[u] = hv; } else hn[u] = h[u];
    }
    #pragma unroll
    for (int u=0;u<25;u++) h[u] = hn[u];
  }
  float* dst = cf + (size_t)w*56 + d*28;   // 16B-aligned for all (w,d)
  #pragma unroll
  for (int u4=0;u4<6;u4++)
    *(float4*)&dst[u4*4] = make_float4(h[u4*4],h[u4*4+1],h[u4*4+2],h[u4*4+3]);
  dst[24] = h[24];
}

// ---------------- Kernel 2: x[p][150] = word_emb[tok[p]] ++ cf[recover[p]] (cf stride 56)
__global__ void k_buildx(const int* __restrict__ tok, const int* __restrict__ recover,
                         const float* __restrict__ word_emb, const float* __restrict__ cf,
                         float* __restrict__ x){
  long i = (long)blockIdx.x*blockDim.x + threadIdx.x;
  if (i >= (long)NWORDS*DWd) return;
  int p = (int)(i/DWd); int e = (int)(i - (long)p*DWd);
  float v;
  if (e < WEd) v = word_emb[(long)tok[p]*WEd + e];
  else {
    int cidx = e - WEd;           // 0..49
    int dd = cidx / 25; int uu = cidx - dd*25;
    v = cf[(size_t)recover[p]*56 + dd*28 + uu];
  }
  x[i] = v;
}

// ---------------- Kernel 3: gx[d][p][400] = wb_d + x[p] @ wWih_d (fp32 tiled, M=16384,N=800,K=150)
__global__ __launch_bounds__(256) void k_wih(const float* __restrict__ x,
    const float* __restrict__ Wf, const float* __restrict__ bf,
    const float* __restrict__ Wb, const float* __restrict__ bbias,
    float* __restrict__ gx){
  __shared__ float As[150][36];
  int tid = threadIdx.x;
  int m0 = (blockIdx.x>>2)*32;
  int nt = blockIdx.x & 3;
  int n0 = nt*256;
  for (int i=tid; i<32*150; i+=256){
    int r = i/150; int k = i - r*150;
    As[k][r] = x[(long)(m0+r)*150 + k];
  }
  __syncthreads();
  int tn = tid & 31; int tm = tid >> 5;
  int j0 = n0 + tn*8;
  bool colok = j0 < 800;
  int d = (j0 >= 400) ? 1 : 0;
  const float* W = d ? Wb : Wf;
  int jc = j0 - d*400;
  float acc[4][8];
  #pragma unroll
  for (int mi=0;mi<4;mi++)
    #pragma unroll
    for (int ni=0;ni<8;ni++) acc[mi][ni]=0.f;
  if (colok){
    for (int k=0;k<150;k++){
      float4 b0 = *(const float4*)&W[k*400 + jc];
      float4 b1 = *(const float4*)&W[k*400 + jc + 4];
      float4 a4 = *(const float4*)&As[k][tm*4];
      float av[4] = {a4.x,a4.y,a4.z,a4.w};
      float bv[8] = {b0.x,b0.y,b0.z,b0.w,b1.x,b1.y,b1.z,b1.w};
      #pragma unroll
      for (int mi=0;mi<4;mi++)
        #pragma unroll
        for (int ni=0;ni<8;ni++) acc[mi][ni] += av[mi]*bv[ni];
    }
    const float* bptr = d ? bbias : bf;
    float bias[8];
    #pragma unroll
    for (int ni=0;ni<8;ni++) bias[ni] = bptr[jc+ni];
    #pragma unroll
    for (int mi=0;mi<4;mi++){
      int p = m0 + tm*4 + mi;
      float* orow = gx + ((long)d*NWORDS + p)*400 + jc;
      #pragma unroll
      for (int ni=0;ni<8;ni++) orow[ni] = acc[mi][ni] + bias[ni];
    }
  }
}

// ---------------- Kernel 4: word LSTM recurrence.
// block = (seq, dir), 256 threads. Thread j<200 owns cols 2j,2j+1: 200 weights
// pinned in VGPRs by staging global->LDS->regs (ds_read can't be rematerialized;
// 512-reg budget at 4 waves -> no spill). h broadcast via uniform ds_read_b128.
__global__ __launch_bounds__(256, 1) void k_wlstm(const float* __restrict__ gx,
     const float* __restrict__ Whf, const float* __restrict__ Whb,
     float* __restrict__ hseq){
  __shared__ float wstage[10000];   // 25 rows x 400 cols, 40KB chunk
  __shared__ float h_lds[104];
  __shared__ float act[400];
  int tid = threadIdx.x;
  int s = blockIdx.x & 63; int d = blockIdx.x >> 6;
  const float* Wh = d ? Whb : Whf;
  int j0 = 2*tid;
  float wA[100], wB[100];
  #pragma unroll
  for (int ch=0; ch<4; ch++){
    for (int i=tid; i<2500; i+=256)
      ((float4*)wstage)[i] = ((const float4*)(Wh + ch*10000))[i];
    __syncthreads();
    if (tid < 200){
      #pragma unroll
      for (int kk=0;kk<25;kk++){
        float2 wv = *(const float2*)&wstage[kk*400 + j0];
        wA[ch*25+kk] = wv.x; wB[ch*25+kk] = wv.y;
      }
    }
    __syncthreads();
  }
  if (tid < 104) h_lds[tid] = 0.f;
  float c_reg = 0.f;
  const float* gxd = gx + ((long)d*NWORDS + (long)s*256)*400;
  int region = tid/50;   // 0=i,1=f,2=g,3=o
  __syncthreads();
  float2 gnext = make_float2(0.f, 0.f);
  if (tid < 200){
    int t0 = d ? 255 : 0;
    gnext = *(const float2*)&gxd[t0*400 + j0];
  }
  for (int t=0;t<256;t++){
    float2 gcur = gnext;
    if (tid < 200 && t+1 < 256){
      int tn = d ? (255-(t+1)) : (t+1);
      gnext = *(const float2*)&gxd[tn*400 + j0];
    }
    if (tid < 200){
      float ax = gcur.x, ay = gcur.y;
      #pragma unroll
      for (int kq=0;kq<25;kq++){
        float4 hq = *(const float4*)&h_lds[4*kq];
        ax += hq.x*wA[4*kq]   + hq.y*wA[4*kq+1] + hq.z*wA[4*kq+2] + hq.w*wA[4*kq+3];
        ay += hq.x*wB[4*kq]   + hq.y*wB[4*kq+1] + hq.z*wB[4*kq+2] + hq.w*wB[4*kq+3];
      }
      float2 v;
      if (region == 2){ v.x = tanhf_(ax); v.y = tanhf_(ay); }
      else            { v.x = sigf(ax);   v.y = sigf(ay);  }
      *(float2*)&act[j0] = v;
    }
    __syncthreads();   // act visible; all h_lds reads of this step done
    if (tid < 100){
      float si = act[tid], sf = act[100+tid], sg = act[200+tid], so = act[300+tid];
      c_reg = sf*c_reg + si*sg;
      float hv = so*tanhf_(c_reg);
      h_lds[tid] = hv;
      int ttc = d ? (255-t) : t;
      hseq[((long)d*NWORDS + s*256 + ttc)*100 + tid] = hv;
    }
    __syncthreads();   // new h visible
  }
}

// ---------------- Kernel 5: emissions em[p][25] = b_tag + concat(h_f,h_b)[p] @ W_tag
__global__ __launch_bounds__(256) void k_em(const float* __restrict__ hseq,
    const float* __restrict__ Wtag, const float* __restrict__ btag,
    float* __restrict__ em){
  __shared__ float hrow[8][200];
  __shared__ float Ws[5000];
  int tid = threadIdx.x;
  for (int i=tid;i<5000;i+=256) Ws[i] = Wtag[i];
  int p0 = blockIdx.x*8;
  for (int i=tid;i<8*200;i+=256){
    int r = i/200; int k = i - r*200;
    int p = p0+r;
    hrow[r][k] = (k<100) ? hseq[(long)p*100+k] : hseq[((long)NWORDS + p)*100 + (k-100)];
  }
  __syncthreads();
  int r = tid>>5; int c = tid&31;
  if (c<25){
    float acc = btag[c];
    for (int k=0;k<200;k++) acc += hrow[r][k]*Ws[k*25+c];
    em[(long)(p0+r)*25 + c] = acc;
  }
}

// ---------------- Kernel 6: CRF per sequence: part[s] = logZ - gold.
__global__ __launch_bounds__(64) void k_crf(const float* __restrict__ em,
    const int* __restrict__ tag, const float* __restrict__ trans,
    const float* __restrict__ start, const float* __restrict__ endv,
    float* __restrict__ part){
  int s = blockIdx.x;
  int lane = threadIdx.x;
  int j = lane & 31; int kg = lane >> 5;
  int k0 = kg ? 13 : 0; int kcnt = kg ? 12 : 13;
  const float* emb = em + (long)s*256*25;
  float tr[13];
  #pragma unroll
  for (int kk=0;kk<13;kk++){
    int k = k0+kk;
    tr[kk] = (k<25 && j<25) ? trans[k*25+j] : 0.f;
  }
  float alpha = (j<25) ? (start[j] + emb[j]) : -1e30f;
  float enext = (j<25) ? emb[25 + j] : 0.f;
  for (int t=1;t<256;t++){
    float ecur = enext;
    if (t<255 && j<25) enext = emb[(t+1)*25 + j];
    float m = -1e30f;
    #pragma unroll
    for (int kk=0;kk<13;kk++){
      if (kk<kcnt){
        float a = __shfl(alpha, k0+kk, 64);
        m = fmaxf(m, a + tr[kk]);
      }
    }
    m = fmaxf(m, __shfl_xor(m, 32, 64));
    float ssum = 0.f;
    #pragma unroll
    for (int kk=0;kk<13;kk++){
      if (kk<kcnt){
        float a = __shfl(alpha, k0+kk, 64);
        ssum += __expf(a + tr[kk] - m);
      }
    }
    ssum += __shfl_xor(ssum, 32, 64);
    float anew = __logf(ssum) + m + ecur;
    alpha = (j<25) ? anew : -1e30f;
  }
  float val = (j<25 && kg==0) ? (alpha + endv[j]) : -1e30f;
  float m2 = -1e30f;
  for (int k=0;k<25;k++) m2 = fmaxf(m2, __shfl(val, k, 64));
  float s2 = 0.f;
  for (int k=0;k<25;k++) s2 += __expf(__shfl(val, k, 64) - m2);
  float logZ = __logf(s2) + m2;
  const int* tg = tag + s*256;
  float gp = 0.f;
  for (int t=lane; t<256; t+=64){
    int a = tg[t];
    gp += emb[t*25 + a];
    if (t<255) gp += trans[a*25 + tg[t+1]];
  }
  #pragma unroll
  for (int off=32; off; off>>=1) gp += __shfl_xor(gp, off, 64);
  if (lane==0){
    float gold = gp + start[tg[0]] + endv[tg[255]];
    part[s] = logZ - gold;
  }
}

// ---------------- Kernel 7: final reduce
__global__ __launch_bounds__(64) void k_red(const float* __restrict__ part, float* __restrict__ out){
  float v = part[threadIdx.x];
  #pragma unroll
  for (int off=32; off; off>>=1) v += __shfl_xor(v, off, 64);
  if (threadIdx.x==0) out[0] = v;
}

extern "C" void kernel_launch(void* const* d_in, const int* in_sizes, int n_in,
                              void* d_out, int out_size, void* d_ws, size_t ws_size,
                              hipStream_t stream){
  const int* tok          = (const int*)d_in[0];
  const int* tagp         = (const int*)d_in[1];
  const int* char_tensor  = (const int*)d_in[3];
  const int* char_lengths = (const int*)d_in[4];
  const int* recover      = (const int*)d_in[5];
  const float* word_emb = (const float*)d_in[6];
  const float* char_emb = (const float*)d_in[7];
  const float* cWih_f=(const float*)d_in[8];  const float* cWhh_f=(const float*)d_in[9];  const float* cb_f=(const float*)d_in[10];
  const float* cWih_b=(const float*)d_in[11]; const float* cWhh_b=(const float*)d_in[12]; const float* cb_b=(const float*)d_in[13];
  const float* wWih_f=(const float*)d_in[14]; const float* wWhh_f=(const float*)d_in[15]; const float* wb_f=(const float*)d_in[16];
  const float* wWih_b=(const float*)d_in[17]; const float* wWhh_b=(const float*)d_in[18]; const float* wb_b=(const float*)d_in[19];
  const float* W_tag=(const float*)d_in[20];  const float* b_tag=(const float*)d_in[21];
  const float* trans=(const float*)d_in[22];  const float* startv=(const float*)d_in[23]; const float* endv=(const float*)d_in[24];

  float* ws  = (float*)d_ws;
  float* gxc = ws;                 // 25600
  float* cf  = ws + 25600;         // 16384*56 = 917504
  float* x   = ws + 943104;        // 2457600
  float* gx  = ws + 3400704;       // 13107200
  float* hseq= ws + 16507904;      // 3276800  (high water: 19784704)
  float* em  = ws + 943104;        // overlays x (dead after k_wih), 409600
  float* part= ws + 19784704;      // 64
  float* out = (float*)d_out;

  k_gxc   <<<100, 256, 0, stream>>>(char_emb, cWih_f, cb_f, cWih_b, cb_b, gxc);
  k_char  <<<512, 64,  0, stream>>>(char_tensor, char_lengths, cWhh_f, cWhh_b, gxc, cf);
  k_buildx<<<9600,256, 0, stream>>>(tok, recover, word_emb, cf, x);
  k_wih   <<<2048,256, 0, stream>>>(x, wWih_f, wb_f, wWih_b, wb_b, gx);
  k_wlstm <<<128, 256, 0, stream>>>(gx, wWhh_f, wWhh_b, hseq);
  k_em    <<<2048,256, 0, stream>>>(hseq, W_tag, b_tag, em);
  k_crf   <<<64,  64,  0, stream>>>(em, tagp, trans, startv, endv, part);
  k_red   <<<1,   64,  0, stream>>>(part, out);
}

// Round 4
// 909.637 us; speedup vs baseline: 2.5496x; 2.5496x over previous
//
#include <hip/hip_runtime.h>
#include <hip/hip_bf16.h>

// Problem constants
#define NB 64
#define NT 256
#define TC 16
#define NL 25
#define NWORDS 16384   // NB*NT
#define DWd 150        // word-LSTM input dim
#define WEd 100

__device__ __forceinline__ float sigf(float x){ return __fdividef(1.f, 1.f + __expf(-x)); }
__device__ __forceinline__ float tanhf_(float x){
    float ax = fabsf(x);
    float e = __expf(-2.f*ax);                 // e in (0,1], overflow-safe
    float r = (1.f - e) * __fdividef(1.f, 1.f + e);
    return copysignf(r, x);
}

// ---------------- Kernel 0: gxc[c][d][u][q] = cb[q*25+u] + sum_k char_emb[c][k]*cWih[k][q*25+u]
__global__ void k_gxc(const float* __restrict__ char_emb,
                      const float* __restrict__ cWih_f, const float* __restrict__ cb_f,
                      const float* __restrict__ cWih_b, const float* __restrict__ cb_b,
                      float* __restrict__ gxc){
  int i = blockIdx.x*blockDim.x + threadIdx.x;
  if (i >= 128*2*25*4) return;
  int q = i & 3; int t = i >> 2; int u = t % 25; int t2 = t / 25; int d = t2 & 1; int c = t2 >> 1;
  const float* Wih = d ? cWih_b : cWih_f;
  const float* bb  = d ? cb_b  : cb_f;
  int col = q*25 + u;
  float acc = bb[col];
  #pragma unroll
  for (int k=0;k<25;k++) acc += char_emb[c*25+k]*Wih[k*100+col];
  gxc[i] = acc;
}

// ---------------- Kernel 0b: whT[d][u][k][q] = cWhh_d[k*100 + q*25 + u]  (scalar-path weight table)
__global__ void k_whT(const float* __restrict__ cWhh_f, const float* __restrict__ cWhh_b,
                      float* __restrict__ whT){
  int i = blockIdx.x*blockDim.x + threadIdx.x;
  if (i >= 5000) return;
  int q = i & 3; int t = i >> 2; int k = t % 25; int t2 = t / 25; int u = t2 % 25; int d = t2 / 25;
  const float* W = d ? cWhh_b : cWhh_f;
  whT[i] = W[k*100 + q*25 + u];
}

// ---------------- Kernel 1: char BiLSTM, lane = (word,dir) chain. h/c in VGPRs.
// Weights via WAVE-UNIFORM loads from whT -> s_load + v_fmac(v,s,v): never touch
// VGPR file or LDS. No LDS, no barriers. launch_bounds(64,1) -> 512-reg budget,
// no spill (grid only supplies 2 waves/CU anyway).
__global__ __launch_bounds__(64, 1) void k_char(const int* __restrict__ char_tensor,
   const int* __restrict__ char_lengths,
   const float* __restrict__ whT,
   const float* __restrict__ gxc, float* __restrict__ cf){
  int lane = threadIdx.x;
  int gw = blockIdx.x;          // 0..511
  int d  = gw >> 8;
  int w  = (gw & 255) * 64 + lane;
  const float* Wd = whT + d*2500;
  int len = char_lengths[w];
  const int* crow = char_tensor + w*TC;
  float h[25], c[25];
  #pragma unroll
  for (int u=0;u<25;u++){ h[u]=0.f; c[u]=0.f; }
  for (int t=0;t<TC;t++){
    bool active = (t < len);
    int ci = d ? (len-1-t) : t;
    if (ci < 0) ci = 0;
    int cidx = crow[ci];
    const float4* gx4 = (const float4*)(gxc + (size_t)(cidx*2+d)*100);
    float hn[25];
    #pragma unroll
    for (int u=0;u<25;u++){
      float4 a = gx4[u];
      #pragma unroll
      for (int k=0;k<25;k++){
        // uniform address -> scalar loads; broadcast via VALU scalar operand
        a.x += h[k]*Wd[(u*25+k)*4+0];
        a.y += h[k]*Wd[(u*25+k)*4+1];
        a.z += h[k]*Wd[(u*25+k)*4+2];
        a.w += h[k]*Wd[(u*25+k)*4+3];
      }
      float cn = sigf(a.y)*c[u] + sigf(a.x)*tanhf_(a.z);
      float hv = sigf(a.w)*tanhf_(cn);
      hn[u] = active ? hv : h[u];
      c[u]  = active ? cn : c[u];
    }
    #pragma unroll
    for (int u=0;u<25;u++) h[u] = hn[u];
  }
  float* dst = cf + (size_t)w*56 + d*28;   // 16B-aligned for all (w,d)
  #pragma unroll
  for (int u4=0;u4<6;u4++)
    *(float4*)&dst[u4*4] = make_float4(h[u4*4],h[u4*4+1],h[u4*4+2],h[u4*4+3]);
  dst[24] = h[24];
}

// ---------------- Kernel 2: x[p][150] = word_emb[tok[p]] ++ cf[recover[p]] (cf stride 56)
__global__ void k_buildx(const int* __restrict__ tok, const int* __restrict__ recover,
                         const float* __restrict__ word_emb, const float* __restrict__ cf,
                         float* __restrict__ x){
  long i = (long)blockIdx.x*blockDim.x + threadIdx.x;
  if (i >= (long)NWORDS*DWd) return;
  int p = (int)(i/DWd); int e = (int)(i - (long)p*DWd);
  float v;
  if (e < WEd) v = word_emb[(long)tok[p]*WEd + e];
  else {
    int cidx = e - WEd;           // 0..49
    int dd = cidx / 25; int uu = cidx - dd*25;
    v = cf[(size_t)recover[p]*56 + dd*28 + uu];
  }
  x[i] = v;
}

// ---------------- Kernel 3: gx[d][p][400] = wb_d + x[p] @ wWih_d (fp32 tiled, M=16384,N=800,K=150)
__global__ __launch_bounds__(256) void k_wih(const float* __restrict__ x,
    const float* __restrict__ Wf, const float* __restrict__ bf,
    const float* __restrict__ Wb, const float* __restrict__ bbias,
    float* __restrict__ gx){
  __shared__ float As[150][36];
  int tid = threadIdx.x;
  int m0 = (blockIdx.x>>2)*32;
  int nt = blockIdx.x & 3;
  int n0 = nt*256;
  for (int i=tid; i<32*150; i+=256){
    int r = i/150; int k = i - r*150;
    As[k][r] = x[(long)(m0+r)*150 + k];
  }
  __syncthreads();
  int tn = tid & 31; int tm = tid >> 5;
  int j0 = n0 + tn*8;
  bool colok = j0 < 800;
  int d = (j0 >= 400) ? 1 : 0;
  const float* W = d ? Wb : Wf;
  int jc = j0 - d*400;
  float acc[4][8];
  #pragma unroll
  for (int mi=0;mi<4;mi++)
    #pragma unroll
    for (int ni=0;ni<8;ni++) acc[mi][ni]=0.f;
  if (colok){
    for (int k=0;k<150;k++){
      float4 b0 = *(const float4*)&W[k*400 + jc];
      float4 b1 = *(const float4*)&W[k*400 + jc + 4];
      float4 a4 = *(const float4*)&As[k][tm*4];
      float av[4] = {a4.x,a4.y,a4.z,a4.w};
      float bv[8] = {b0.x,b0.y,b0.z,b0.w,b1.x,b1.y,b1.z,b1.w};
      #pragma unroll
      for (int mi=0;mi<4;mi++)
        #pragma unroll
        for (int ni=0;ni<8;ni++) acc[mi][ni] += av[mi]*bv[ni];
    }
    const float* bptr = d ? bbias : bf;
    float bias[8];
    #pragma unroll
    for (int ni=0;ni<8;ni++) bias[ni] = bptr[jc+ni];
    #pragma unroll
    for (int mi=0;mi<4;mi++){
      int p = m0 + tm*4 + mi;
      float* orow = gx + ((long)d*NWORDS + p)*400 + jc;
      #pragma unroll
      for (int ni=0;ni<8;ni++) orow[ni] = acc[mi][ni] + bias[ni];
    }
  }
}

// ---------------- Kernel 4: word LSTM recurrence.
// block = (seq, dir), 256 threads. Thread j<200 owns cols 2j,2j+1: 200 weights
// pinned in VGPRs by staging global->LDS->regs. h broadcast via uniform ds_read_b128.
__global__ __launch_bounds__(256, 1) void k_wlstm(const float* __restrict__ gx,
     const float* __restrict__ Whf, const float* __restrict__ Whb,
     float* __restrict__ hseq){
  __shared__ float wstage[10000];   // 25 rows x 400 cols, 40KB chunk
  __shared__ float h_lds[104];
  __shared__ float act[400];
  int tid = threadIdx.x;
  int s = blockIdx.x & 63; int d = blockIdx.x >> 6;
  const float* Wh = d ? Whb : Whf;
  int j0 = 2*tid;
  float wA[100], wB[100];
  #pragma unroll
  for (int ch=0; ch<4; ch++){
    for (int i=tid; i<2500; i+=256)
      ((float4*)wstage)[i] = ((const float4*)(Wh + ch*10000))[i];
    __syncthreads();
    if (tid < 200){
      #pragma unroll
      for (int kk=0;kk<25;kk++){
        float2 wv = *(const float2*)&wstage[kk*400 + j0];
        wA[ch*25+kk] = wv.x; wB[ch*25+kk] = wv.y;
      }
    }
    __syncthreads();
  }
  if (tid < 104) h_lds[tid] = 0.f;
  float c_reg = 0.f;
  const float* gxd = gx + ((long)d*NWORDS + (long)s*256)*400;
  int region = tid/50;   // 0=i,1=f,2=g,3=o
  __syncthreads();
  float2 gnext = make_float2(0.f, 0.f);
  if (tid < 200){
    int t0 = d ? 255 : 0;
    gnext = *(const float2*)&gxd[t0*400 + j0];
  }
  for (int t=0;t<256;t++){
    float2 gcur = gnext;
    if (tid < 200 && t+1 < 256){
      int tn = d ? (255-(t+1)) : (t+1);
      gnext = *(const float2*)&gxd[tn*400 + j0];
    }
    if (tid < 200){
      float ax = gcur.x, ay = gcur.y;
      #pragma unroll
      for (int kq=0;kq<25;kq++){
        float4 hq = *(const float4*)&h_lds[4*kq];
        ax += hq.x*wA[4*kq]   + hq.y*wA[4*kq+1] + hq.z*wA[4*kq+2] + hq.w*wA[4*kq+3];
        ay += hq.x*wB[4*kq]   + hq.y*wB[4*kq+1] + hq.z*wB[4*kq+2] + hq.w*wB[4*kq+3];
      }
      float2 v;
      if (region == 2){ v.x = tanhf_(ax); v.y = tanhf_(ay); }
      else            { v.x = sigf(ax);   v.y = sigf(ay);  }
      *(float2*)&act[j0] = v;
    }
    __syncthreads();   // act visible; all h_lds reads of this step done
    if (tid < 100){
      float si = act[tid], sf = act[100+tid], sg = act[200+tid], so = act[300+tid];
      c_reg = sf*c_reg + si*sg;
      float hv = so*tanhf_(c_reg);
      h_lds[tid] = hv;
      int ttc = d ? (255-t) : t;
      hseq[((long)d*NWORDS + s*256 + ttc)*100 + tid] = hv;
    }
    __syncthreads();   // new h visible
  }
}

// ---------------- Kernel 5: emissions em[p][25] = b_tag + concat(h_f,h_b)[p] @ W_tag
__global__ __launch_bounds__(256) void k_em(const float* __restrict__ hseq,
    const float* __restrict__ Wtag, const float* __restrict__ btag,
    float* __restrict__ em){
  __shared__ float hrow[8][200];
  __shared__ float Ws[5000];
  int tid = threadIdx.x;
  for (int i=tid;i<5000;i+=256) Ws[i] = Wtag[i];
  int p0 = blockIdx.x*8;
  for (int i=tid;i<8*200;i+=256){
    int r = i/200; int k = i - r*200;
    int p = p0+r;
    hrow[r][k] = (k<100) ? hseq[(long)p*100+k] : hseq[((long)NWORDS + p)*100 + (k-100)];
  }
  __syncthreads();
  int r = tid>>5; int c = tid&31;
  if (c<25){
    float acc = btag[c];
    for (int k=0;k<200;k++) acc += hrow[r][k]*Ws[k*25+c];
    em[(long)(p0+r)*25 + c] = acc;
  }
}

// ---------------- Kernel 6: CRF per sequence: part[s] = logZ - gold.
__global__ __launch_bounds__(64) void k_crf(const float* __restrict__ em,
    const int* __restrict__ tag, const float* __restrict__ trans,
    const float* __restrict__ start, const float* __restrict__ endv,
    float* __restrict__ part){
  int s = blockIdx.x;
  int lane = threadIdx.x;
  int j = lane & 31; int kg = lane >> 5;
  int k0 = kg ? 13 : 0; int kcnt = kg ? 12 : 13;
  const float* emb = em + (long)s*256*25;
  float tr[13];
  #pragma unroll
  for (int kk=0;kk<13;kk++){
    int k = k0+kk;
    tr[kk] = (k<25 && j<25) ? trans[k*25+j] : 0.f;
  }
  float alpha = (j<25) ? (start[j] + emb[j]) : -1e30f;
  float enext = (j<25) ? emb[25 + j] : 0.f;
  for (int t=1;t<256;t++){
    float ecur = enext;
    if (t<255 && j<25) enext = emb[(t+1)*25 + j];
    float m = -1e30f;
    #pragma unroll
    for (int kk=0;kk<13;kk++){
      if (kk<kcnt){
        float a = __shfl(alpha, k0+kk, 64);
        m = fmaxf(m, a + tr[kk]);
      }
    }
    m = fmaxf(m, __shfl_xor(m, 32, 64));
    float ssum = 0.f;
    #pragma unroll
    for (int kk=0;kk<13;kk++){
      if (kk<kcnt){
        float a = __shfl(alpha, k0+kk, 64);
        ssum += __expf(a + tr[kk] - m);
      }
    }
    ssum += __shfl_xor(ssum, 32, 64);
    float anew = __logf(ssum) + m + ecur;
    alpha = (j<25) ? anew : -1e30f;
  }
  float val = (j<25 && kg==0) ? (alpha + endv[j]) : -1e30f;
  float m2 = -1e30f;
  for (int k=0;k<25;k++) m2 = fmaxf(m2, __shfl(val, k, 64));
  float s2 = 0.f;
  for (int k=0;k<25;k++) s2 += __expf(__shfl(val, k, 64) - m2);
  float logZ = __logf(s2) + m2;
  const int* tg = tag + s*256;
  float gp = 0.f;
  for (int t=lane; t<256; t+=64){
    int a = tg[t];
    gp += emb[t*25 + a];
    if (t<255) gp += trans[a*25 + tg[t+1]];
  }
  #pragma unroll
  for (int off=32; off; off>>=1) gp += __shfl_xor(gp, off, 64);
  if (lane==0){
    float gold = gp + start[tg[0]] + endv[tg[255]];
    part[s] = logZ - gold;
  }
}

// ---------------- Kernel 7: final reduce
__global__ __launch_bounds__(64) void k_red(const float* __restrict__ part, float* __restrict__ out){
  float v = part[threadIdx.x];
  #pragma unroll
  for (int off=32; off; off>>=1) v += __shfl_xor(v, off, 64);
  if (threadIdx.x==0) out[0] = v;
}

extern "C" void kernel_launch(void* const* d_in, const int* in_sizes, int n_in,
                              void* d_out, int out_size, void* d_ws, size_t ws_size,
                              hipStream_t stream){
  const int* tok          = (const int*)d_in[0];
  const int* tagp         = (const int*)d_in[1];
  const int* char_tensor  = (const int*)d_in[3];
  const int* char_lengths = (const int*)d_in[4];
  const int* recover      = (const int*)d_in[5];
  const float* word_emb = (const float*)d_in[6];
  const float* char_emb = (const float*)d_in[7];
  const float* cWih_f=(const float*)d_in[8];  const float* cWhh_f=(const float*)d_in[9];  const float* cb_f=(const float*)d_in[10];
  const float* cWih_b=(const float*)d_in[11]; const float* cWhh_b=(const float*)d_in[12]; const float* cb_b=(const float*)d_in[13];
  const float* wWih_f=(const float*)d_in[14]; const float* wWhh_f=(const float*)d_in[15]; const float* wb_f=(const float*)d_in[16];
  const float* wWih_b=(const float*)d_in[17]; const float* wWhh_b=(const float*)d_in[18]; const float* wb_b=(const float*)d_in[19];
  const float* W_tag=(const float*)d_in[20];  const float* b_tag=(const float*)d_in[21];
  const float* trans=(const float*)d_in[22];  const float* startv=(const float*)d_in[23]; const float* endv=(const float*)d_in[24];

  float* ws  = (float*)d_ws;
  float* gxc = ws;                 // 25600
  float* cf  = ws + 25600;         // 16384*56 = 917504
  float* x   = ws + 943104;        // 2457600
  float* gx  = ws + 3400704;       // 13107200
  float* hseq= ws + 16507904;      // 3276800
  float* em  = ws + 943104;        // overlays x (dead after k_wih), 409600
  float* part= ws + 19784704;      // 64
  float* whT = ws + 19784768;      // 5000   (high water: 19789768 floats = 79.2 MB)
  float* out = (float*)d_out;

  k_gxc   <<<100, 256, 0, stream>>>(char_emb, cWih_f, cb_f, cWih_b, cb_b, gxc);
  k_whT   <<<20,  256, 0, stream>>>(cWhh_f, cWhh_b, whT);
  k_char  <<<512, 64,  0, stream>>>(char_tensor, char_lengths, whT, gxc, cf);
  k_buildx<<<9600,256, 0, stream>>>(tok, recover, word_emb, cf, x);
  k_wih   <<<2048,256, 0, stream>>>(x, wWih_f, wb_f, wWih_b, wb_b, gx);
  k_wlstm <<<128, 256, 0, stream>>>(gx, wWhh_f, wWhh_b, hseq);
  k_em    <<<2048,256, 0, stream>>>(hseq, W_tag, b_tag, em);
  k_crf   <<<64,  64,  0, stream>>>(em, tagp, trans, startv, endv, part);
  k_red   <<<1,   64,  0, stream>>>(part, out);
}

// Round 5
// 698.595 us; speedup vs baseline: 3.3198x; 1.3021x over previous
//
#include <hip/hip_runtime.h>
#include <hip/hip_bf16.h>

// Problem constants
#define NB 64
#define NT 256
#define TC 16
#define NL 25
#define NWORDS 16384   // NB*NT
#define DWd 150        // word-LSTM input dim
#define WEd 100
#define WPB 5          // words per k_char block

__device__ __forceinline__ float sigf(float x){ return __fdividef(1.f, 1.f + __expf(-x)); }
__device__ __forceinline__ float tanhf_(float x){
    float ax = fabsf(x);
    float e = __expf(-2.f*ax);                 // e in (0,1], overflow-safe
    float r = (1.f - e) * __fdividef(1.f, 1.f + e);
    return copysignf(r, x);
}

// ---------------- Kernel 0: gxc[(c,d)][col] = cb_d[col] + sum_k char_emb[c][k]*cWih_d[k*100+col]
// col = q*25+u (PyTorch gate-col order) -> k_char gather is coalesced in col.
__global__ void k_gxc(const float* __restrict__ char_emb,
                      const float* __restrict__ cWih_f, const float* __restrict__ cb_f,
                      const float* __restrict__ cWih_b, const float* __restrict__ cb_b,
                      float* __restrict__ gxc){
  int i = blockIdx.x*blockDim.x + threadIdx.x;
  if (i >= 128*2*100) return;
  int col = i % 100; int d = (i/100) & 1; int c = i/200;
  const float* Wih = d ? cWih_b : cWih_f;
  const float* bb  = d ? cb_b  : cb_f;
  float acc = bb[col];
  #pragma unroll
  for (int k=0;k<25;k++) acc += char_emb[c*25+k]*Wih[k*100+col];
  gxc[i] = acc;
}

// ---------------- Kernel 1: char BiLSTM, thread = (word_in_block, gate_col).
// block = 512 thr = 5 words x 100 cols, one dir; grid = 3277*2 blocks.
// Weights: wcol[25] VGPRs/thread (coalesced load). h: LDS broadcast (float4,
// <=2 distinct addrs/wave). All 16 gxc gathers prefetched to regs before the
// time loop (indices depend only on len). 2 barriers/step.
__global__ __launch_bounds__(512) void k_char(const int* __restrict__ char_tensor,
   const int* __restrict__ char_lengths,
   const float* __restrict__ cWhh_f, const float* __restrict__ cWhh_b,
   const float* __restrict__ gxc, float* __restrict__ cf){
  __shared__ float h_lds[WPB][28];    // rows padded to 28 (16B-aligned float4 reads)
  __shared__ float act[WPB][100];
  __shared__ int   chars[WPB][TC];
  __shared__ int   lens[WPB];
  int tid = threadIdx.x;
  int d  = blockIdx.x & 1;
  int wb = blockIdx.x >> 1;           // 0..3276
  int w0 = wb*WPB;
  if (tid < WPB*TC){
    int ww = w0 + tid/TC;
    int cw = ww < NWORDS ? ww : NWORDS-1;
    chars[tid/TC][tid%TC] = char_tensor[cw*TC + (tid%TC)];
  }
  if (tid < WPB){
    int ww = w0 + tid;
    lens[tid] = char_lengths[ww < NWORDS ? ww : NWORDS-1];
  }
  int wsub = tid/100;                 // 0..4 for tid<500
  int j    = tid - wsub*100;          // gate col 0..99
  bool gate_thr = tid < WPB*100;
  const float* Wh = d ? cWhh_b : cWhh_f;
  float wcol[25];
  if (gate_thr){
    #pragma unroll
    for (int k=0;k<25;k++) wcol[k] = Wh[k*100 + j];
  }
  if (gate_thr && j < 28) h_lds[wsub][j] = 0.f;
  float c_reg = 0.f, h_last = 0.f;
  __syncthreads();
  int len = gate_thr ? lens[wsub] : 1;
  bool isg = (j >= 50) && (j < 75);
  // prefetch all 16 gate inputs for this (word, col)
  float g_all[TC];
  if (gate_thr){
    #pragma unroll
    for (int t=0;t<TC;t++){
      int ci = d ? (len-1-t) : t;
      if (ci < 0 || ci >= TC) ci = 0;
      int cidx = chars[wsub][ci];
      g_all[t] = gxc[(size_t)(cidx*2+d)*100 + j];
    }
  }
  for (int t=0;t<TC;t++){
    if (gate_thr){
      float a = g_all[t];
      const float4* h4 = (const float4*)h_lds[wsub];
      #pragma unroll
      for (int kq=0;kq<6;kq++){
        float4 hq = h4[kq];
        a += hq.x*wcol[4*kq] + hq.y*wcol[4*kq+1] + hq.z*wcol[4*kq+2] + hq.w*wcol[4*kq+3];
      }
      a += h_lds[wsub][24]*wcol[24];
      act[wsub][j] = isg ? tanhf_(a) : sigf(a);
    }
    __syncthreads();   // act ready; h reads of this step done
    if (gate_thr && j < 25 && t < len){
      float si = act[wsub][j], sf = act[wsub][25+j], sg = act[wsub][50+j], so = act[wsub][75+j];
      c_reg = sf*c_reg + si*sg;
      float hv = so*tanhf_(c_reg);
      h_lds[wsub][j] = hv;
      h_last = hv;
    }
    __syncthreads();   // new h visible
  }
  if (gate_thr && j < 25){
    int w = w0 + wsub;
    if (w < NWORDS) cf[(size_t)w*56 + d*28 + j] = h_last;
  }
}

// ---------------- Kernel 2: x[p][150] = word_emb[tok[p]] ++ cf[recover[p]] (cf stride 56)
__global__ void k_buildx(const int* __restrict__ tok, const int* __restrict__ recover,
                         const float* __restrict__ word_emb, const float* __restrict__ cf,
                         float* __restrict__ x){
  long i = (long)blockIdx.x*blockDim.x + threadIdx.x;
  if (i >= (long)NWORDS*DWd) return;
  int p = (int)(i/DWd); int e = (int)(i - (long)p*DWd);
  float v;
  if (e < WEd) v = word_emb[(long)tok[p]*WEd + e];
  else {
    int cidx = e - WEd;           // 0..49
    int dd = cidx / 25; int uu = cidx - dd*25;
    v = cf[(size_t)recover[p]*56 + dd*28 + uu];
  }
  x[i] = v;
}

// ---------------- Kernel 3: gx[d][p][400] = wb_d + x[p] @ wWih_d (fp32 tiled, M=16384,N=800,K=150)
__global__ __launch_bounds__(256) void k_wih(const float* __restrict__ x,
    const float* __restrict__ Wf, const float* __restrict__ bf,
    const float* __restrict__ Wb, const float* __restrict__ bbias,
    float* __restrict__ gx){
  __shared__ float As[150][36];
  int tid = threadIdx.x;
  int m0 = (blockIdx.x>>2)*32;
  int nt = blockIdx.x & 3;
  int n0 = nt*256;
  for (int i=tid; i<32*150; i+=256){
    int r = i/150; int k = i - r*150;
    As[k][r] = x[(long)(m0+r)*150 + k];
  }
  __syncthreads();
  int tn = tid & 31; int tm = tid >> 5;
  int j0 = n0 + tn*8;
  bool colok = j0 < 800;
  int d = (j0 >= 400) ? 1 : 0;
  const float* W = d ? Wb : Wf;
  int jc = j0 - d*400;
  float acc[4][8];
  #pragma unroll
  for (int mi=0;mi<4;mi++)
    #pragma unroll
    for (int ni=0;ni<8;ni++) acc[mi][ni]=0.f;
  if (colok){
    for (int k=0;k<150;k++){
      float4 b0 = *(const float4*)&W[k*400 + jc];
      float4 b1 = *(const float4*)&W[k*400 + jc + 4];
      float4 a4 = *(const float4*)&As[k][tm*4];
      float av[4] = {a4.x,a4.y,a4.z,a4.w};
      float bv[8] = {b0.x,b0.y,b0.z,b0.w,b1.x,b1.y,b1.z,b1.w};
      #pragma unroll
      for (int mi=0;mi<4;mi++)
        #pragma unroll
        for (int ni=0;ni<8;ni++) acc[mi][ni] += av[mi]*bv[ni];
    }
    const float* bptr = d ? bbias : bf;
    float bias[8];
    #pragma unroll
    for (int ni=0;ni<8;ni++) bias[ni] = bptr[jc+ni];
    #pragma unroll
    for (int mi=0;mi<4;mi++){
      int p = m0 + tm*4 + mi;
      float* orow = gx + ((long)d*NWORDS + p)*400 + jc;
      #pragma unroll
      for (int ni=0;ni<8;ni++) orow[ni] = acc[mi][ni] + bias[ni];
    }
  }
}

// ---------------- Kernel 4: word LSTM recurrence.
// block = (seq, dir), 256 threads. Thread j<200 owns cols 2j,2j+1: 200 weights
// pinned in VGPRs by staging global->LDS->regs. h broadcast via uniform ds_read_b128.
__global__ __launch_bounds__(256, 1) void k_wlstm(const float* __restrict__ gx,
     const float* __restrict__ Whf, const float* __restrict__ Whb,
     float* __restrict__ hseq){
  __shared__ float wstage[10000];   // 25 rows x 400 cols, 40KB chunk
  __shared__ float h_lds[104];
  __shared__ float act[400];
  int tid = threadIdx.x;
  int s = blockIdx.x & 63; int d = blockIdx.x >> 6;
  const float* Wh = d ? Whb : Whf;
  int j0 = 2*tid;
  float wA[100], wB[100];
  #pragma unroll
  for (int ch=0; ch<4; ch++){
    for (int i=tid; i<2500; i+=256)
      ((float4*)wstage)[i] = ((const float4*)(Wh + ch*10000))[i];
    __syncthreads();
    if (tid < 200){
      #pragma unroll
      for (int kk=0;kk<25;kk++){
        float2 wv = *(const float2*)&wstage[kk*400 + j0];
        wA[ch*25+kk] = wv.x; wB[ch*25+kk] = wv.y;
      }
    }
    __syncthreads();
  }
  if (tid < 104) h_lds[tid] = 0.f;
  float c_reg = 0.f;
  const float* gxd = gx + ((long)d*NWORDS + (long)s*256)*400;
  int region = tid/50;   // 0=i,1=f,2=g,3=o
  __syncthreads();
  float2 gnext = make_float2(0.f, 0.f);
  if (tid < 200){
    int t0 = d ? 255 : 0;
    gnext = *(const float2*)&gxd[t0*400 + j0];
  }
  for (int t=0;t<256;t++){
    float2 gcur = gnext;
    if (tid < 200 && t+1 < 256){
      int tn = d ? (255-(t+1)) : (t+1);
      gnext = *(const float2*)&gxd[tn*400 + j0];
    }
    if (tid < 200){
      float ax = gcur.x, ay = gcur.y;
      #pragma unroll
      for (int kq=0;kq<25;kq++){
        float4 hq = *(const float4*)&h_lds[4*kq];
        ax += hq.x*wA[4*kq]   + hq.y*wA[4*kq+1] + hq.z*wA[4*kq+2] + hq.w*wA[4*kq+3];
        ay += hq.x*wB[4*kq]   + hq.y*wB[4*kq+1] + hq.z*wB[4*kq+2] + hq.w*wB[4*kq+3];
      }
      float2 v;
      if (region == 2){ v.x = tanhf_(ax); v.y = tanhf_(ay); }
      else            { v.x = sigf(ax);   v.y = sigf(ay);  }
      *(float2*)&act[j0] = v;
    }
    __syncthreads();   // act visible; all h_lds reads of this step done
    if (tid < 100){
      float si = act[tid], sf = act[100+tid], sg = act[200+tid], so = act[300+tid];
      c_reg = sf*c_reg + si*sg;
      float hv = so*tanhf_(c_reg);
      h_lds[tid] = hv;
      int ttc = d ? (255-t) : t;
      hseq[((long)d*NWORDS + s*256 + ttc)*100 + tid] = hv;
    }
    __syncthreads();   // new h visible
  }
}

// ---------------- Kernel 5: emissions em[p][25] = b_tag + concat(h_f,h_b)[p] @ W_tag
__global__ __launch_bounds__(256) void k_em(const float* __restrict__ hseq,
    const float* __restrict__ Wtag, const float* __restrict__ btag,
    float* __restrict__ em){
  __shared__ float hrow[8][200];
  __shared__ float Ws[5000];
  int tid = threadIdx.x;
  for (int i=tid;i<5000;i+=256) Ws[i] = Wtag[i];
  int p0 = blockIdx.x*8;
  for (int i=tid;i<8*200;i+=256){
    int r = i/200; int k = i - r*200;
    int p = p0+r;
    hrow[r][k] = (k<100) ? hseq[(long)p*100+k] : hseq[((long)NWORDS + p)*100 + (k-100)];
  }
  __syncthreads();
  int r = tid>>5; int c = tid&31;
  if (c<25){
    float acc = btag[c];
    for (int k=0;k<200;k++) acc += hrow[r][k]*Ws[k*25+c];
    em[(long)(p0+r)*25 + c] = acc;
  }
}

// ---------------- Kernel 6: CRF per sequence: part[s] = logZ - gold.
__global__ __launch_bounds__(64) void k_crf(const float* __restrict__ em,
    const int* __restrict__ tag, const float* __restrict__ trans,
    const float* __restrict__ start, const float* __restrict__ endv,
    float* __restrict__ part){
  int s = blockIdx.x;
  int lane = threadIdx.x;
  int j = lane & 31; int kg = lane >> 5;
  int k0 = kg ? 13 : 0; int kcnt = kg ? 12 : 13;
  const float* emb = em + (long)s*256*25;
  float tr[13];
  #pragma unroll
  for (int kk=0;kk<13;kk++){
    int k = k0+kk;
    tr[kk] = (k<25 && j<25) ? trans[k*25+j] : 0.f;
  }
  float alpha = (j<25) ? (start[j] + emb[j]) : -1e30f;
  float enext = (j<25) ? emb[25 + j] : 0.f;
  for (int t=1;t<256;t++){
    float ecur = enext;
    if (t<255 && j<25) enext = emb[(t+1)*25 + j];
    float m = -1e30f;
    #pragma unroll
    for (int kk=0;kk<13;kk++){
      if (kk<kcnt){
        float a = __shfl(alpha, k0+kk, 64);
        m = fmaxf(m, a + tr[kk]);
      }
    }
    m = fmaxf(m, __shfl_xor(m, 32, 64));
    float ssum = 0.f;
    #pragma unroll
    for (int kk=0;kk<13;kk++){
      if (kk<kcnt){
        float a = __shfl(alpha, k0+kk, 64);
        ssum += __expf(a + tr[kk] - m);
      }
    }
    ssum += __shfl_xor(ssum, 32, 64);
    float anew = __logf(ssum) + m + ecur;
    alpha = (j<25) ? anew : -1e30f;
  }
  float val = (j<25 && kg==0) ? (alpha + endv[j]) : -1e30f;
  float m2 = -1e30f;
  for (int k=0;k<25;k++) m2 = fmaxf(m2, __shfl(val, k, 64));
  float s2 = 0.f;
  for (int k=0;k<25;k++) s2 += __expf(__shfl(val, k, 64) - m2);
  float logZ = __logf(s2) + m2;
  const int* tg = tag + s*256;
  float gp = 0.f;
  for (int t=lane; t<256; t+=64){
    int a = tg[t];
    gp += emb[t*25 + a];
    if (t<255) gp += trans[a*25 + tg[t+1]];
  }
  #pragma unroll
  for (int off=32; off; off>>=1) gp += __shfl_xor(gp, off, 64);
  if (lane==0){
    float gold = gp + start[tg[0]] + endv[tg[255]];
    part[s] = logZ - gold;
  }
}

// ---------------- Kernel 7: final reduce
__global__ __launch_bounds__(64) void k_red(const float* __restrict__ part, float* __restrict__ out){
  float v = part[threadIdx.x];
  #pragma unroll
  for (int off=32; off; off>>=1) v += __shfl_xor(v, off, 64);
  if (threadIdx.x==0) out[0] = v;
}

extern "C" void kernel_launch(void* const* d_in, const int* in_sizes, int n_in,
                              void* d_out, int out_size, void* d_ws, size_t ws_size,
                              hipStream_t stream){
  const int* tok          = (const int*)d_in[0];
  const int* tagp         = (const int*)d_in[1];
  const int* char_tensor  = (const int*)d_in[3];
  const int* char_lengths = (const int*)d_in[4];
  const int* recover      = (const int*)d_in[5];
  const float* word_emb = (const float*)d_in[6];
  const float* char_emb = (const float*)d_in[7];
  const float* cWih_f=(const float*)d_in[8];  const float* cWhh_f=(const float*)d_in[9];  const float* cb_f=(const float*)d_in[10];
  const float* cWih_b=(const float*)d_in[11]; const float* cWhh_b=(const float*)d_in[12]; const float* cb_b=(const float*)d_in[13];
  const float* wWih_f=(const float*)d_in[14]; const float* wWhh_f=(const float*)d_in[15]; const float* wb_f=(const float*)d_in[16];
  const float* wWih_b=(const float*)d_in[17]; const float* wWhh_b=(const float*)d_in[18]; const float* wb_b=(const float*)d_in[19];
  const float* W_tag=(const float*)d_in[20];  const float* b_tag=(const float*)d_in[21];
  const float* trans=(const float*)d_in[22];  const float* startv=(const float*)d_in[23]; const float* endv=(const float*)d_in[24];

  float* ws  = (float*)d_ws;
  float* gxc = ws;                 // 25600
  float* cf  = ws + 25600;         // 16384*56 = 917504
  float* x   = ws + 943104;        // 2457600
  float* gx  = ws + 3400704;       // 13107200
  float* hseq= ws + 16507904;      // 3276800
  float* em  = ws + 943104;        // overlays x (dead after k_wih), 409600
  float* part= ws + 19784704;      // 64   (high water ~79.1 MB)
  float* out = (float*)d_out;

  k_gxc   <<<100, 256, 0, stream>>>(char_emb, cWih_f, cb_f, cWih_b, cb_b, gxc);
  k_char  <<<6554,512, 0, stream>>>(char_tensor, char_lengths, cWhh_f, cWhh_b, gxc, cf);
  k_buildx<<<9600,256, 0, stream>>>(tok, recover, word_emb, cf, x);
  k_wih   <<<2048,256, 0, stream>>>(x, wWih_f, wb_f, wWih_b, wb_b, gx);
  k_wlstm <<<128, 256, 0, stream>>>(gx, wWhh_f, wWhh_b, hseq);
  k_em    <<<2048,256, 0, stream>>>(hseq, W_tag, b_tag, em);
  k_crf   <<<64,  64,  0, stream>>>(em, tagp, trans, startv, endv, part);
  k_red   <<<1,   64,  0, stream>>>(part, out);
}

// Round 6
// 617.820 us; speedup vs baseline: 3.7539x; 1.1307x over previous
//
#include <hip/hip_runtime.h>
#include <hip/hip_bf16.h>

// Problem constants
#define NB 64
#define NT 256
#define TC 16
#define NL 25
#define NWORDS 16384   // NB*NT
#define DWd 150        // word-LSTM input dim
#define WEd 100
#define WPB 5          // words per k_char block

__device__ __forceinline__ float sigf(float x){ return __fdividef(1.f, 1.f + __expf(-x)); }
__device__ __forceinline__ float tanhf_(float x){
    float ax = fabsf(x);
    float e = __expf(-2.f*ax);                 // e in (0,1], overflow-safe
    float r = (1.f - e) * __fdividef(1.f, 1.f + e);
    return copysignf(r, x);
}

// ---------------- Kernel 0: gxc[(c,d)][col] = cb_d[col] + sum_k char_emb[c][k]*cWih_d[k*100+col]
__global__ void k_gxc(const float* __restrict__ char_emb,
                      const float* __restrict__ cWih_f, const float* __restrict__ cb_f,
                      const float* __restrict__ cWih_b, const float* __restrict__ cb_b,
                      float* __restrict__ gxc){
  int i = blockIdx.x*blockDim.x + threadIdx.x;
  if (i >= 128*2*100) return;
  int col = i % 100; int d = (i/100) & 1; int c = i/200;
  const float* Wih = d ? cWih_b : cWih_f;
  const float* bb  = d ? cb_b  : cb_f;
  float acc = bb[col];
  #pragma unroll
  for (int k=0;k<25;k++) acc += char_emb[c*25+k]*Wih[k*100+col];
  gxc[i] = acc;
}

// ---------------- Kernel 1: char BiLSTM, thread = (word_in_block, gate_col).
__global__ __launch_bounds__(512) void k_char(const int* __restrict__ char_tensor,
   const int* __restrict__ char_lengths,
   const float* __restrict__ cWhh_f, const float* __restrict__ cWhh_b,
   const float* __restrict__ gxc, float* __restrict__ cf){
  __shared__ float h_lds[WPB][28];    // rows padded to 28 (16B-aligned float4 reads)
  __shared__ float act[WPB][100];
  __shared__ int   chars[WPB][TC];
  __shared__ int   lens[WPB];
  int tid = threadIdx.x;
  int d  = blockIdx.x & 1;
  int wb = blockIdx.x >> 1;           // 0..3276
  int w0 = wb*WPB;
  if (tid < WPB*TC){
    int ww = w0 + tid/TC;
    int cw = ww < NWORDS ? ww : NWORDS-1;
    chars[tid/TC][tid%TC] = char_tensor[cw*TC + (tid%TC)];
  }
  if (tid < WPB){
    int ww = w0 + tid;
    lens[tid] = char_lengths[ww < NWORDS ? ww : NWORDS-1];
  }
  int wsub = tid/100;                 // 0..4 for tid<500
  int j    = tid - wsub*100;          // gate col 0..99
  bool gate_thr = tid < WPB*100;
  const float* Wh = d ? cWhh_b : cWhh_f;
  float wcol[25];
  if (gate_thr){
    #pragma unroll
    for (int k=0;k<25;k++) wcol[k] = Wh[k*100 + j];
  }
  if (gate_thr && j < 28) h_lds[wsub][j] = 0.f;
  float c_reg = 0.f, h_last = 0.f;
  __syncthreads();
  int len = gate_thr ? lens[wsub] : 1;
  bool isg = (j >= 50) && (j < 75);
  float g_all[TC];
  if (gate_thr){
    #pragma unroll
    for (int t=0;t<TC;t++){
      int ci = d ? (len-1-t) : t;
      if (ci < 0 || ci >= TC) ci = 0;
      int cidx = chars[wsub][ci];
      g_all[t] = gxc[(size_t)(cidx*2+d)*100 + j];
    }
  }
  for (int t=0;t<TC;t++){
    if (gate_thr){
      float a = g_all[t];
      const float4* h4 = (const float4*)h_lds[wsub];
      #pragma unroll
      for (int kq=0;kq<6;kq++){
        float4 hq = h4[kq];
        a += hq.x*wcol[4*kq] + hq.y*wcol[4*kq+1] + hq.z*wcol[4*kq+2] + hq.w*wcol[4*kq+3];
      }
      a += h_lds[wsub][24]*wcol[24];
      act[wsub][j] = isg ? tanhf_(a) : sigf(a);
    }
    __syncthreads();
    if (gate_thr && j < 25 && t < len){
      float si = act[wsub][j], sf = act[wsub][25+j], sg = act[wsub][50+j], so = act[wsub][75+j];
      c_reg = sf*c_reg + si*sg;
      float hv = so*tanhf_(c_reg);
      h_lds[wsub][j] = hv;
      h_last = hv;
    }
    __syncthreads();
  }
  if (gate_thr && j < 25){
    int w = w0 + wsub;
    if (w < NWORDS) cf[(size_t)w*56 + d*28 + j] = h_last;
  }
}

// ---------------- Kernel 2: x[p][150] = word_emb[tok[p]] ++ cf[recover[p]] (cf stride 56)
__global__ void k_buildx(const int* __restrict__ tok, const int* __restrict__ recover,
                         const float* __restrict__ word_emb, const float* __restrict__ cf,
                         float* __restrict__ x){
  long i = (long)blockIdx.x*blockDim.x + threadIdx.x;
  if (i >= (long)NWORDS*DWd) return;
  int p = (int)(i/DWd); int e = (int)(i - (long)p*DWd);
  float v;
  if (e < WEd) v = word_emb[(long)tok[p]*WEd + e];
  else {
    int cidx = e - WEd;           // 0..49
    int dd = cidx / 25; int uu = cidx - dd*25;
    v = cf[(size_t)recover[p]*56 + dd*28 + uu];
  }
  x[i] = v;
}

// ---------------- Kernel 3: gx[d][p][400] = wb_d + x[p] @ wWih_d (fp32 tiled, M=16384,N=800,K=150)
__global__ __launch_bounds__(256) void k_wih(const float* __restrict__ x,
    const float* __restrict__ Wf, const float* __restrict__ bf,
    const float* __restrict__ Wb, const float* __restrict__ bbias,
    float* __restrict__ gx){
  __shared__ float As[150][36];
  int tid = threadIdx.x;
  int m0 = (blockIdx.x>>2)*32;
  int nt = blockIdx.x & 3;
  int n0 = nt*256;
  for (int i=tid; i<32*150; i+=256){
    int r = i/150; int k = i - r*150;
    As[k][r] = x[(long)(m0+r)*150 + k];
  }
  __syncthreads();
  int tn = tid & 31; int tm = tid >> 5;
  int j0 = n0 + tn*8;
  bool colok = j0 < 800;
  int d = (j0 >= 400) ? 1 : 0;
  const float* W = d ? Wb : Wf;
  int jc = j0 - d*400;
  float acc[4][8];
  #pragma unroll
  for (int mi=0;mi<4;mi++)
    #pragma unroll
    for (int ni=0;ni<8;ni++) acc[mi][ni]=0.f;
  if (colok){
    for (int k=0;k<150;k++){
      float4 b0 = *(const float4*)&W[k*400 + jc];
      float4 b1 = *(const float4*)&W[k*400 + jc + 4];
      float4 a4 = *(const float4*)&As[k][tm*4];
      float av[4] = {a4.x,a4.y,a4.z,a4.w};
      float bv[8] = {b0.x,b0.y,b0.z,b0.w,b1.x,b1.y,b1.z,b1.w};
      #pragma unroll
      for (int mi=0;mi<4;mi++)
        #pragma unroll
        for (int ni=0;ni<8;ni++) acc[mi][ni] += av[mi]*bv[ni];
    }
    const float* bptr = d ? bbias : bf;
    float bias[8];
    #pragma unroll
    for (int ni=0;ni<8;ni++) bias[ni] = bptr[jc+ni];
    #pragma unroll
    for (int mi=0;mi<4;mi++){
      int p = m0 + tm*4 + mi;
      float* orow = gx + ((long)d*NWORDS + p)*400 + jc;
      #pragma unroll
      for (int ni=0;ni<8;ni++) orow[ni] = acc[mi][ni] + bias[ni];
    }
  }
}

// ---------------- Kernel 4: word LSTM recurrence v4.
// block = (seq, dir), 448 threads (7 waves -> 2 waves/SIMD). Thread j<400 owns
// ONE gate column: wreg[100] VGPRs (staged global->LDS->reg to defeat remat;
// launch_bounds(448,2) caps regs at 256 so no AGPR pressure). h broadcast via
// 25 uniform ds_read_b128. 2 barriers/step, single-buffered h/act (race-free).
__global__ __launch_bounds__(448, 2) void k_wlstm(const float* __restrict__ gx,
     const float* __restrict__ Whf, const float* __restrict__ Whb,
     float* __restrict__ hseq){
  __shared__ float wstage[10000];   // 25 rows x 400 cols, 40KB chunk
  __shared__ float h_lds[100];
  __shared__ float act[400];
  int tid = threadIdx.x;
  int s = blockIdx.x & 63; int d = blockIdx.x >> 6;
  const float* Wh = d ? Whb : Whf;
  int j = tid;
  bool colthr = j < 400;
  float wreg[100];
  #pragma unroll
  for (int ch=0; ch<4; ch++){
    for (int i=tid; i<2500; i+=448)
      ((float4*)wstage)[i] = ((const float4*)(Wh + ch*10000))[i];
    __syncthreads();
    if (colthr){
      #pragma unroll
      for (int kk=0;kk<25;kk++) wreg[ch*25+kk] = wstage[kk*400 + j];
    }
    __syncthreads();
  }
  if (tid < 100) h_lds[tid] = 0.f;
  float c_reg = 0.f;
  const float* gxd = gx + ((long)d*NWORDS + (long)s*256)*400;
  bool isg = (j >= 200) && (j < 300);
  __syncthreads();
  float gnext = 0.f;
  if (colthr) gnext = gxd[(d?255:0)*400 + j];
  for (int t=0;t<256;t++){
    float gcur = gnext;
    if (colthr && t+1 < 256){
      int tn = d ? (255-(t+1)) : (t+1);
      gnext = gxd[tn*400 + j];
    }
    if (colthr){
      float a = gcur;
      const float4* h4 = (const float4*)h_lds;
      #pragma unroll
      for (int kq=0;kq<25;kq++){
        float4 hq = h4[kq];
        a += hq.x*wreg[4*kq] + hq.y*wreg[4*kq+1] + hq.z*wreg[4*kq+2] + hq.w*wreg[4*kq+3];
      }
      act[j] = isg ? tanhf_(a) : sigf(a);
    }
    __syncthreads();   // act visible; all h_lds reads of this step done
    if (tid < 100){
      float si = act[tid], sf = act[100+tid], sg = act[200+tid], so = act[300+tid];
      c_reg = sf*c_reg + si*sg;
      float hv = so*tanhf_(c_reg);
      h_lds[tid] = hv;
      int ttc = d ? (255-t) : t;
      hseq[((long)d*NWORDS + s*256 + ttc)*100 + tid] = hv;
    }
    __syncthreads();   // new h visible
  }
}

// ---------------- Kernel 5: emissions em[p][25] = b_tag + concat(h_f,h_b)[p] @ W_tag
__global__ __launch_bounds__(256) void k_em(const float* __restrict__ hseq,
    const float* __restrict__ Wtag, const float* __restrict__ btag,
    float* __restrict__ em){
  __shared__ float hrow[8][200];
  __shared__ float Ws[5000];
  int tid = threadIdx.x;
  for (int i=tid;i<5000;i+=256) Ws[i] = Wtag[i];
  int p0 = blockIdx.x*8;
  for (int i=tid;i<8*200;i+=256){
    int r = i/200; int k = i - r*200;
    int p = p0+r;
    hrow[r][k] = (k<100) ? hseq[(long)p*100+k] : hseq[((long)NWORDS + p)*100 + (k-100)];
  }
  __syncthreads();
  int r = tid>>5; int c = tid&31;
  if (c<25){
    float acc = btag[c];
    for (int k=0;k<200;k++) acc += hrow[r][k]*Ws[k*25+c];
    em[(long)(p0+r)*25 + c] = acc;
  }
}

// ---------------- Kernel 6: CRF per sequence: part[s] = logZ - gold.
__global__ __launch_bounds__(64) void k_crf(const float* __restrict__ em,
    const int* __restrict__ tag, const float* __restrict__ trans,
    const float* __restrict__ start, const float* __restrict__ endv,
    float* __restrict__ part){
  int s = blockIdx.x;
  int lane = threadIdx.x;
  int j = lane & 31; int kg = lane >> 5;
  int k0 = kg ? 13 : 0; int kcnt = kg ? 12 : 13;
  const float* emb = em + (long)s*256*25;
  float tr[13];
  #pragma unroll
  for (int kk=0;kk<13;kk++){
    int k = k0+kk;
    tr[kk] = (k<25 && j<25) ? trans[k*25+j] : 0.f;
  }
  float alpha = (j<25) ? (start[j] + emb[j]) : -1e30f;
  float enext = (j<25) ? emb[25 + j] : 0.f;
  for (int t=1;t<256;t++){
    float ecur = enext;
    if (t<255 && j<25) enext = emb[(t+1)*25 + j];
    float m = -1e30f;
    #pragma unroll
    for (int kk=0;kk<13;kk++){
      if (kk<kcnt){
        float a = __shfl(alpha, k0+kk, 64);
        m = fmaxf(m, a + tr[kk]);
      }
    }
    m = fmaxf(m, __shfl_xor(m, 32, 64));
    float ssum = 0.f;
    #pragma unroll
    for (int kk=0;kk<13;kk++){
      if (kk<kcnt){
        float a = __shfl(alpha, k0+kk, 64);
        ssum += __expf(a + tr[kk] - m);
      }
    }
    ssum += __shfl_xor(ssum, 32, 64);
    float anew = __logf(ssum) + m + ecur;
    alpha = (j<25) ? anew : -1e30f;
  }
  float val = (j<25 && kg==0) ? (alpha + endv[j]) : -1e30f;
  float m2 = -1e30f;
  for (int k=0;k<25;k++) m2 = fmaxf(m2, __shfl(val, k, 64));
  float s2 = 0.f;
  for (int k=0;k<25;k++) s2 += __expf(__shfl(val, k, 64) - m2);
  float logZ = __logf(s2) + m2;
  const int* tg = tag + s*256;
  float gp = 0.f;
  for (int t=lane; t<256; t+=64){
    int a = tg[t];
    gp += emb[t*25 + a];
    if (t<255) gp += trans[a*25 + tg[t+1]];
  }
  #pragma unroll
  for (int off=32; off; off>>=1) gp += __shfl_xor(gp, off, 64);
  if (lane==0){
    float gold = gp + start[tg[0]] + endv[tg[255]];
    part[s] = logZ - gold;
  }
}

// ---------------- Kernel 7: final reduce
__global__ __launch_bounds__(64) void k_red(const float* __restrict__ part, float* __restrict__ out){
  float v = part[threadIdx.x];
  #pragma unroll
  for (int off=32; off; off>>=1) v += __shfl_xor(v, off, 64);
  if (threadIdx.x==0) out[0] = v;
}

extern "C" void kernel_launch(void* const* d_in, const int* in_sizes, int n_in,
                              void* d_out, int out_size, void* d_ws, size_t ws_size,
                              hipStream_t stream){
  const int* tok          = (const int*)d_in[0];
  const int* tagp         = (const int*)d_in[1];
  const int* char_tensor  = (const int*)d_in[3];
  const int* char_lengths = (const int*)d_in[4];
  const int* recover      = (const int*)d_in[5];
  const float* word_emb = (const float*)d_in[6];
  const float* char_emb = (const float*)d_in[7];
  const float* cWih_f=(const float*)d_in[8];  const float* cWhh_f=(const float*)d_in[9];  const float* cb_f=(const float*)d_in[10];
  const float* cWih_b=(const float*)d_in[11]; const float* cWhh_b=(const float*)d_in[12]; const float* cb_b=(const float*)d_in[13];
  const float* wWih_f=(const float*)d_in[14]; const float* wWhh_f=(const float*)d_in[15]; const float* wb_f=(const float*)d_in[16];
  const float* wWih_b=(const float*)d_in[17]; const float* wWhh_b=(const float*)d_in[18]; const float* wb_b=(const float*)d_in[19];
  const float* W_tag=(const float*)d_in[20];  const float* b_tag=(const float*)d_in[21];
  const float* trans=(const float*)d_in[22];  const float* startv=(const float*)d_in[23]; const float* endv=(const float*)d_in[24];

  float* ws  = (float*)d_ws;
  float* gxc = ws;                 // 25600
  float* cf  = ws + 25600;         // 16384*56 = 917504
  float* x   = ws + 943104;        // 2457600
  float* gx  = ws + 3400704;       // 13107200
  float* hseq= ws + 16507904;      // 3276800
  float* em  = ws + 943104;        // overlays x (dead after k_wih), 409600
  float* part= ws + 19784704;      // 64   (high water ~79.1 MB)
  float* out = (float*)d_out;

  k_gxc   <<<100, 256, 0, stream>>>(char_emb, cWih_f, cb_f, cWih_b, cb_b, gxc);
  k_char  <<<6554,512, 0, stream>>>(char_tensor, char_lengths, cWhh_f, cWhh_b, gxc, cf);
  k_buildx<<<9600,256, 0, stream>>>(tok, recover, word_emb, cf, x);
  k_wih   <<<2048,256, 0, stream>>>(x, wWih_f, wb_f, wWih_b, wb_b, gx);
  k_wlstm <<<128, 448, 0, stream>>>(gx, wWhh_f, wWhh_b, hseq);
  k_em    <<<2048,256, 0, stream>>>(hseq, W_tag, b_tag, em);
  k_crf   <<<64,  64,  0, stream>>>(em, tagp, trans, startv, endv, part);
  k_red   <<<1,   64,  0, stream>>>(part, out);
}